// Round 18
// baseline (777.988 us; speedup 1.0000x reference)
//
#include <hip/hip_runtime.h>
#include <cstdint>
#include <cstddef>

// ---- problem constants ----
static constexpr int BATCH = 32;
static constexpr int CIN   = 3;
static constexpr int HIN   = 224, WIN = 224;
static constexpr int COUT  = 64;
static constexpr int HOUT  = 56, WOUT = 56;
static constexpr int NPIX  = HOUT * WOUT;     // 3136
static constexpr int NEXP  = 8;
static constexpr int KROWS = 21;              // ci*7 + kh
static constexpr int NKS   = 6;               // K-steps of 32
static constexpr int NGRP  = 28;              // 2-oh-row groups per image (112 px)
static constexpr int PWL   = 232;             // window row length (ushorts): 4+224+4
static constexpr int WR    = 11;              // window rows per ci (2*4 + 3)
static constexpr int RAMP  = 16;              // ablation amplification factor
static constexpr float LN_EPS_F = 1e-6f;

// fragment-coalesced weight buffer: [e(9)][f(4)][ks(6)][lane(64)][8]
static constexpr int PW3_ELEMS = 9 * 4 * 6 * 64 * 8;   // 110592

// k_pre partition: gate partial sums (768) + weight repack (432)
static constexpr int N_GPART  = BATCH * CIN * 8;                  // 768
static constexpr int N_REPACK = (PW3_ELEMS + 255) / 256;          // 432

typedef __bf16 bf16x8 __attribute__((ext_vector_type(8)));
typedef float  f32x4  __attribute__((ext_vector_type(4)));

// ---- device-global scratch ----
__device__ __align__(16) ushort g_pw3[PW3_ELEMS];   // bf16 weights, fragment order
__device__ float g_gatepart[BATCH * CIN * 8];       // partial plane sums

__device__ __forceinline__ ushort f2bf(float f) {
  uint u = __float_as_uint(f);
  uint r = (u + 0x7FFFu + ((u >> 16) & 1u)) >> 16;  // RNE
  return (ushort)r;
}

// ---------------- kernel 1: gate partial sums (0..767) / repack (768..1199) ---
__global__ __launch_bounds__(256) void k_pre(const float* __restrict__ x,
                                             const float* __restrict__ eW,
                                             const float* __restrict__ sW) {
  const int bid = blockIdx.x;
  if (bid < N_GPART) {
    const int plane = bid >> 3;
    const int slice = bid & 7;
    const float4* p4 = reinterpret_cast<const float4*>(x + (size_t)plane * (HIN * WIN));
    float s = 0.f;
    const int i0 = slice * 1568;                // 12544/8 float4 per slice
    for (int i = i0 + (int)threadIdx.x; i < i0 + 1568; i += 256) {
      const float4 v = p4[i];
      s += v.x + v.y + v.z + v.w;
    }
    __shared__ float red[256];
    red[threadIdx.x] = s;
    __syncthreads();
    for (int off = 128; off > 0; off >>= 1) {
      if ((int)threadIdx.x < off) red[threadIdx.x] += red[threadIdx.x + off];
      __syncthreads();
    }
    if (threadIdx.x == 0) g_gatepart[bid] = red[0];
  } else {
    const int idx = (bid - N_GPART) * 256 + threadIdx.x;
    if (idx >= PW3_ELEMS) return;
    const int j    = idx & 7;
    const int lane = (idx >> 3) & 63;
    const int ks   = (idx >> 9) % 6;
    const int fe   = idx / (512 * 6);   // e*4 + f
    const int f    = fe & 3;
    const int e    = fe >> 2;
    const int m    = lane >> 4;
    const int colA = lane & 15;
    const int co   = f * 16 + colA;
    const int r    = ks * 4 + m;
    float v = 0.f;
    if (j >= 1 && r < KROWS) {
      const int k = r * 7 + (j - 1);
      v = (e < 8) ? eW[(size_t)(e * COUT + co) * 147 + k]
                  : sW[(size_t)co * 147 + k];
    }
    g_pw3[idx] = f2bf(v);
  }
}

// ---------------- ablation kernel: V selects which phase is amplified x16 -----
// V=0: full real kernel (R17 semantics, writes out+loss). V=1: stage x16.
// V=2: gating x16. V=3: A-load+MFMA x16. V=4: epilogue x16. V=5: stores x16.
// V!=0 variants write only keep-alive garbage (out is fully rewritten by V=0,
// which launches LAST).
template<int V>
__global__ __launch_bounds__(448, 3) void k_abl(
    const float* __restrict__ x,
    const float* __restrict__ w_gate,
    const float* __restrict__ eB, const float* __restrict__ sB,
    const float* __restrict__ elnw, const float* __restrict__ elnb,
    const float* __restrict__ slnw, const float* __restrict__ slnb,
    float* __restrict__ out, float* __restrict__ loss_out) {
  __shared__ __align__(16) ushort Wnd[3 * WR * PWL];   // 15312 B

  const int tid  = threadIdx.x;
  const int lane = tid & 63;
  const int w    = tid >> 6;
  const int b    = blockIdx.x / NGRP;
  const int G    = blockIdx.x % NGRP;

  // ---- STAGE phase (amplified for V==1) ----
  #pragma unroll 1
  for (int rep = 0; rep < ((V == 1) ? RAMP : 1); ++rep) {
    for (int i = tid; i < 3 * WR * 28; i += 448) {
      const int j8 = i % 28;
      const int rr = i / 28;              // ci*11 + wr
      const int ci = rr / WR;
      const int wr = rr - ci * WR;
      const int ih = 8 * G + wr - 3;
      uint2 lo = {0u, 0u}, hi = {0u, 0u};
      if ((unsigned)ih < (unsigned)HIN) {
        const float4* xr = reinterpret_cast<const float4*>(
            x + ((size_t)(b * CIN + ci) * HIN + ih) * WIN);
        const float4 f0 = xr[2 * j8];
        const float4 f1 = xr[2 * j8 + 1];
        lo.x = (uint)f2bf(f0.x) | ((uint)f2bf(f0.y) << 16);
        lo.y = (uint)f2bf(f0.z) | ((uint)f2bf(f0.w) << 16);
        hi.x = (uint)f2bf(f1.x) | ((uint)f2bf(f1.y) << 16);
        hi.y = (uint)f2bf(f1.z) | ((uint)f2bf(f1.w) << 16);
      }
      *reinterpret_cast<uint2*>(&Wnd[rr * PWL + 8 * j8 + 4]) = lo;
      *reinterpret_cast<uint2*>(&Wnd[rr * PWL + 8 * j8 + 8]) = hi;
      if (j8 == 0)  { const uint2 z = {0u, 0u}; *reinterpret_cast<uint2*>(&Wnd[rr * PWL]) = z; }
      if (j8 == 27) { const uint2 z = {0u, 0u}; *reinterpret_cast<uint2*>(&Wnd[rr * PWL + 228]) = z; }
    }
    if (V == 1) __asm__ volatile("" ::: "memory");
  }

  // ---- GATING phase (amplified for V==2) ----
  float g1 = 0.f, g2 = 0.f;
  int e1 = 0, e2 = 1;
  float gsink = 0.f;
  #pragma unroll 1
  for (int rep = 0; rep < ((V == 2) ? RAMP : 1); ++rep) {
    float gi[3];
    #pragma unroll
    for (int c = 0; c < 3; ++c) {
      float s = 0.f;
      #pragma unroll
      for (int p = 0; p < 8; ++p) s += g_gatepart[(b * 3 + c) * 8 + p];
      gi[c] = s * (1.f / (float)(HIN * WIN));
    }
    float best1 = -1e30f, best2 = -1e30f;
    int i1 = 0, i2 = 0;
    #pragma unroll
    for (int e = 0; e < NEXP; ++e) {
      const float lg = gi[0] * w_gate[e] + gi[1] * w_gate[8 + e] + gi[2] * w_gate[16 + e];
      if (lg > best1) { best2 = best1; i2 = i1; best1 = lg; i1 = e; }
      else if (lg > best2) { best2 = lg; i2 = e; }
    }
    const float e21 = expf(best2 - best1);
    g1 = 1.f / (1.f + e21);
    g2 = e21 / (1.f + e21);
    e1 = __builtin_amdgcn_readfirstlane(i1);
    e2 = __builtin_amdgcn_readfirstlane(i2);
    if (V == 2) {
      gsink += g1 + g2 + (float)(e1 + e2);
      __asm__ volatile("" : "+v"(gsink) :: "memory");
    }
  }

  // ---- loss: only the real kernel ----
  if (V == 0 && blockIdx.x == 0 && w == 0) {
    float mg1 = 0.f, mg2 = 0.f;
    int me1 = -1, me2 = -1;
    if (lane < BATCH) {
      float a[3];
      #pragma unroll
      for (int c = 0; c < 3; ++c) {
        float s = 0.f;
        #pragma unroll
        for (int p = 0; p < 8; ++p) s += g_gatepart[(lane * 3 + c) * 8 + p];
        a[c] = s * (1.f / (float)(HIN * WIN));
      }
      float b1 = -1e30f, b2 = -1e30f;
      int j1 = 0, j2 = 0;
      #pragma unroll
      for (int e = 0; e < NEXP; ++e) {
        const float lg = a[0] * w_gate[e] + a[1] * w_gate[8 + e] + a[2] * w_gate[16 + e];
        if (lg > b1) { b2 = b1; j2 = j1; b1 = lg; j1 = e; }
        else if (lg > b2) { b2 = lg; j2 = e; }
      }
      const float q = expf(b2 - b1);
      mg1 = 1.f / (1.f + q); mg2 = q / (1.f + q);
      me1 = j1; me2 = j2;
    }
    float imp[NEXP], lod[NEXP];
    #pragma unroll
    for (int e = 0; e < NEXP; ++e) {
      float ie = ((me1 == e) ? mg1 : 0.f) + ((me2 == e) ? mg2 : 0.f);
      float le = (((me1 == e) && (mg1 > 0.f)) ? 1.f : 0.f)
               + (((me2 == e) && (mg2 > 0.f)) ? 1.f : 0.f);
      #pragma unroll
      for (int o = 32; o > 0; o >>= 1) { ie += __shfl_xor(ie, o, 64); le += __shfl_xor(le, o, 64); }
      imp[e] = ie; lod[e] = le;
    }
    if (lane == 0) {
      float mi = 0.f, ml = 0.f;
      #pragma unroll
      for (int e = 0; e < NEXP; ++e) { mi += imp[e]; ml += lod[e]; }
      mi *= (1.f / NEXP); ml *= (1.f / NEXP);
      float vi = 0.f, vl = 0.f;
      #pragma unroll
      for (int e = 0; e < NEXP; ++e) {
        const float di = imp[e] - mi; vi += di * di;
        const float dl = lod[e] - ml; vl += dl * dl;
      }
      vi *= (1.f / (NEXP - 1)); vl *= (1.f / (NEXP - 1));
      loss_out[0] = 0.01f * (vi / (mi * mi + 1e-10f) + vl / (ml * ml + 1e-10f));
    }
  }

  __syncthreads();   // window visible

  if (V == 1 || V == 2) return;   // uniform exit after their amplified phase

  __builtin_amdgcn_s_setprio(1);

  const int m    = lane >> 4;
  const int colA = lane & 15;
  const int eidx[3] = {e1, e2, 8};
  const float ge[3] = {g1, g2, 1.f};

  int Crow[NKS];
  #pragma unroll
  for (int ks = 0; ks < NKS; ++ks) {
    int r = 4 * ks + m;
    r = r > 20 ? 20 : r;
    const int ci = r >= 14 ? 2 : (r >= 7 ? 1 : 0);
    const int kh = r - ci * 7;
    Crow[ks] = (ci * WR + kh) * PWL;
  }

  const int pg = G * 112 + w * 16 + colA;
  const int oh = pg / WOUT;
  const int ow = pg - oh * WOUT;
  const int baseB = ((oh - 2 * G) * 4) * PWL + ow * 4;

  // ---- MFMA phase (amplified for V==3): per-expert acc saved to accAll ----
  f32x4 accAll[3][4];
  float msink = 0.f;
  #pragma unroll 1
  for (int rep = 0; rep < ((V == 3) ? RAMP : 1); ++rep) {
    #pragma unroll
    for (int e = 0; e < 3; ++e) {
      const int es = eidx[e];
      f32x4 acc[4];
      #pragma unroll
      for (int f = 0; f < 4; ++f) acc[f] = (f32x4){0.f, 0.f, 0.f, 0.f};
      const ushort* ape = g_pw3 + (size_t)es * (4 * 6 * 512) + lane * 8;
      bf16x8 aCur0 = __builtin_bit_cast(bf16x8, *reinterpret_cast<const uint4*>(ape + (0 * 6 + 0) * 512));
      bf16x8 aCur1 = __builtin_bit_cast(bf16x8, *reinterpret_cast<const uint4*>(ape + (1 * 6 + 0) * 512));
      bf16x8 aCur2 = __builtin_bit_cast(bf16x8, *reinterpret_cast<const uint4*>(ape + (2 * 6 + 0) * 512));
      bf16x8 aCur3 = __builtin_bit_cast(bf16x8, *reinterpret_cast<const uint4*>(ape + (3 * 6 + 0) * 512));
      #pragma unroll
      for (int ks = 0; ks < NKS; ++ks) {
        bf16x8 aNxt0, aNxt1, aNxt2, aNxt3;
        if (ks < NKS - 1) {
          aNxt0 = __builtin_bit_cast(bf16x8, *reinterpret_cast<const uint4*>(ape + (0 * 6 + ks + 1) * 512));
          aNxt1 = __builtin_bit_cast(bf16x8, *reinterpret_cast<const uint4*>(ape + (1 * 6 + ks + 1) * 512));
          aNxt2 = __builtin_bit_cast(bf16x8, *reinterpret_cast<const uint4*>(ape + (2 * 6 + ks + 1) * 512));
          aNxt3 = __builtin_bit_cast(bf16x8, *reinterpret_cast<const uint4*>(ape + (3 * 6 + ks + 1) * 512));
        }
        const ushort* p = &Wnd[baseB + Crow[ks]];
        const uint2 lo = *reinterpret_cast<const uint2*>(p);
        const uint2 hi = *reinterpret_cast<const uint2*>(p + 4);
        const uint4 raw = {lo.x, lo.y, hi.x, hi.y};
        const bf16x8 bfv = __builtin_bit_cast(bf16x8, raw);
        acc[0] = __builtin_amdgcn_mfma_f32_16x16x32_bf16(aCur0, bfv, acc[0], 0, 0, 0);
        acc[1] = __builtin_amdgcn_mfma_f32_16x16x32_bf16(aCur1, bfv, acc[1], 0, 0, 0);
        acc[2] = __builtin_amdgcn_mfma_f32_16x16x32_bf16(aCur2, bfv, acc[2], 0, 0, 0);
        acc[3] = __builtin_amdgcn_mfma_f32_16x16x32_bf16(aCur3, bfv, acc[3], 0, 0, 0);
        if (ks < NKS - 1) { aCur0 = aNxt0; aCur1 = aNxt1; aCur2 = aNxt2; aCur3 = aNxt3; }
      }
      #pragma unroll
      for (int f = 0; f < 4; ++f) accAll[e][f] = acc[f];
      if (V == 3) msink += acc[0][0] + acc[1][1] + acc[2][2] + acc[3][3];
    }
    if (V == 3) __asm__ volatile("" : "+v"(msink) :: "memory");
  }
  if (V == 3) { __asm__ volatile("" :: "v"(msink)); return; }

  // ---- EPILOGUE phase (amplified for V==4) ----
  float outAcc[16];
  float esink = 0.f;
  #pragma unroll 1
  for (int rep = 0; rep < ((V == 4) ? RAMP : 1); ++rep) {
    #pragma unroll
    for (int j = 0; j < 16; ++j) outAcc[j] = 0.f;
    #pragma unroll
    for (int e = 0; e < 3; ++e) {
      const int es = eidx[e];
      const float* bsrc = (e < 2) ? eB + es * COUT : sB;
      const float* wsrc = (e < 2) ? elnw + es * COUT : slnw;
      const float* csrc = (e < 2) ? elnb + es * COUT : slnb;
      float yv[4][4];
      float s = 0.f, q = 0.f;
      #pragma unroll
      for (int f = 0; f < 4; ++f) {
        const float4 b4 = *reinterpret_cast<const float4*>(bsrc + f * 16 + m * 4);
        #pragma unroll
        for (int r = 0; r < 4; ++r) {
          const float y = accAll[e][f][r] + (&b4.x)[r];
          yv[f][r] = y;
          s += y; q += y * y;
        }
      }
      s += __shfl_xor(s, 16, 64); s += __shfl_xor(s, 32, 64);
      q += __shfl_xor(q, 16, 64); q += __shfl_xor(q, 32, 64);
      const float u  = s * (1.f / 64.f);
      const float vv = q * (1.f / 64.f) - u * u;
      const float rs = rsqrtf(vv + LN_EPS_F);
      #pragma unroll
      for (int f = 0; f < 4; ++f) {
        const float4 lw4 = *reinterpret_cast<const float4*>(wsrc + f * 16 + m * 4);
        const float4 lb4 = *reinterpret_cast<const float4*>(csrc + f * 16 + m * 4);
        #pragma unroll
        for (int r = 0; r < 4; ++r)
          outAcc[f * 4 + r] += ge[e] * ((&lw4.x)[r] * (yv[f][r] - u) * rs + (&lb4.x)[r]);
      }
    }
    if (V == 4) {
      esink += outAcc[0] + outAcc[15];
      __asm__ volatile("" : "+v"(esink) :: "memory");
    }
  }
  if (V == 4) { __asm__ volatile("" :: "v"(esink)); return; }

  __builtin_amdgcn_s_setprio(0);

  // ---- STORE phase (amplified for V==5) ----
  float* const outb = out + (size_t)b * (COUT * NPIX);
  #pragma unroll 1
  for (int rep = 0; rep < ((V == 5) ? RAMP : 1); ++rep) {
    #pragma unroll
    for (int f = 0; f < 4; ++f)
      #pragma unroll
      for (int r = 0; r < 4; ++r)
        __builtin_nontemporal_store(outAcc[f * 4 + r],
            outb + (size_t)(f * 16 + m * 4 + r) * NPIX + pg);
    if (V == 5) __asm__ volatile("" ::: "memory");
  }
}

// ---------------- launch ----------------
extern "C" void kernel_launch(void* const* d_in, const int* in_sizes, int n_in,
                              void* d_out, int out_size, void* d_ws, size_t ws_size,
                              hipStream_t stream) {
  const float* x    = (const float*)d_in[0];
  const float* eW   = (const float*)d_in[1];
  const float* eB   = (const float*)d_in[2];
  const float* elnw = (const float*)d_in[3];
  const float* elnb = (const float*)d_in[4];
  const float* sW   = (const float*)d_in[5];
  const float* sB   = (const float*)d_in[6];
  const float* slnw = (const float*)d_in[7];
  const float* slnb = (const float*)d_in[8];
  const float* wg   = (const float*)d_in[9];
  float* out = (float*)d_out;

  float* loss_ptr = out + (size_t)BATCH * COUT * NPIX;  // element 6422528

  k_pre<<<N_GPART + N_REPACK, 256, 0, stream>>>(x, eW, sW);
  // ablation probes (results discarded; out fully rewritten by k_abl<0> below)
  k_abl<1><<<BATCH * NGRP, 448, 0, stream>>>(x, wg, eB, sB, elnw, elnb, slnw, slnb, out, loss_ptr);
  k_abl<2><<<BATCH * NGRP, 448, 0, stream>>>(x, wg, eB, sB, elnw, elnb, slnw, slnb, out, loss_ptr);
  k_abl<3><<<BATCH * NGRP, 448, 0, stream>>>(x, wg, eB, sB, elnw, elnb, slnw, slnb, out, loss_ptr);
  k_abl<4><<<BATCH * NGRP, 448, 0, stream>>>(x, wg, eB, sB, elnw, elnb, slnw, slnb, out, loss_ptr);
  k_abl<5><<<BATCH * NGRP, 448, 0, stream>>>(x, wg, eB, sB, elnw, elnb, slnw, slnb, out, loss_ptr);
  // the real kernel — last, so out/loss are correct
  k_abl<0><<<BATCH * NGRP, 448, 0, stream>>>(x, wg, eB, sB, elnw, elnb, slnw, slnb, out, loss_ptr);
}

// Round 19
// 42.290 us; speedup vs baseline: 18.3964x; 18.3964x over previous
//
#include <hip/hip_runtime.h>
#include <cstdint>
#include <cstddef>

// ---- problem constants ----
static constexpr int BATCH = 32;
static constexpr int CIN   = 3;
static constexpr int HIN   = 224, WIN = 224;
static constexpr int COUT  = 64;
static constexpr int HOUT  = 56, WOUT = 56;
static constexpr int NPIX  = HOUT * WOUT;     // 3136
static constexpr int NEXP  = 8;
static constexpr int KROWS = 21;              // ci*7 + kh
static constexpr int NKS   = 6;               // K-steps of 32
static constexpr int NGRP  = 28;              // 2-oh-row groups per image (112 px)
static constexpr int PWL   = 232;             // window row length (ushorts): 4+224+4
static constexpr int WR    = 11;              // window rows per ci (2*4 + 3)
static constexpr float LN_EPS_F = 1e-6f;

// fragment-coalesced weight buffer: [e(9)][f(4)][ks(6)][lane(64)][8]
static constexpr int PW3_ELEMS = 9 * 4 * 6 * 64 * 8;   // 110592
static constexpr int EXP_USH   = 4 * 6 * 512;          // 12288 ushorts per expert

// k_pre partition: gate partial sums (768) + weight repack (432)
static constexpr int N_GPART  = BATCH * CIN * 8;                  // 768
static constexpr int N_REPACK = (PW3_ELEMS + 255) / 256;          // 432

typedef __bf16 bf16x8 __attribute__((ext_vector_type(8)));
typedef float  f32x4  __attribute__((ext_vector_type(4)));

// ---- device-global scratch ----
__device__ __align__(16) ushort g_pw3[PW3_ELEMS];   // bf16 weights, fragment order
__device__ float g_gatepart[BATCH * CIN * 8];       // partial plane sums

__device__ __forceinline__ ushort f2bf(float f) {
  uint u = __float_as_uint(f);
  uint r = (u + 0x7FFFu + ((u >> 16) & 1u)) >> 16;  // RNE
  return (ushort)r;
}

// ---------------- kernel 1: gate partial sums (0..767) / repack (768..1199) ---
__global__ __launch_bounds__(256) void k_pre(const float* __restrict__ x,
                                             const float* __restrict__ eW,
                                             const float* __restrict__ sW) {
  const int bid = blockIdx.x;
  if (bid < N_GPART) {
    const int plane = bid >> 3;
    const int slice = bid & 7;
    const float4* p4 = reinterpret_cast<const float4*>(x + (size_t)plane * (HIN * WIN));
    float s = 0.f;
    const int i0 = slice * 1568;                // 12544/8 float4 per slice
    for (int i = i0 + (int)threadIdx.x; i < i0 + 1568; i += 256) {
      const float4 v = p4[i];
      s += v.x + v.y + v.z + v.w;
    }
    __shared__ float red[256];
    red[threadIdx.x] = s;
    __syncthreads();
    for (int off = 128; off > 0; off >>= 1) {
      if ((int)threadIdx.x < off) red[threadIdx.x] += red[threadIdx.x + off];
      __syncthreads();
    }
    if (threadIdx.x == 0) g_gatepart[bid] = red[0];
  } else {
    // repack -> fragment order: idx = ((e*4+f)*6+ks)*512 + lane*8 + j
    const int idx = (bid - N_GPART) * 256 + threadIdx.x;
    if (idx >= PW3_ELEMS) return;
    const int j    = idx & 7;
    const int lane = (idx >> 3) & 63;
    const int ks   = (idx >> 9) % 6;
    const int fe   = idx / (512 * 6);   // e*4 + f
    const int f    = fe & 3;
    const int e    = fe >> 2;
    const int m    = lane >> 4;
    const int colA = lane & 15;
    const int co   = f * 16 + colA;
    const int r    = ks * 4 + m;
    float v = 0.f;
    if (j >= 1 && r < KROWS) {
      const int k = r * 7 + (j - 1);
      v = (e < 8) ? eW[(size_t)(e * COUT + co) * 147 + k]
                  : sW[(size_t)co * 147 + k];
    }
    g_pw3[idx] = f2bf(v);
  }
}

// ---------------- kernel 2: MFMA conv + LN + combine, A-in-LDS ---------------
// 896 blocks x 448 threads (7 waves), 2 blocks/CU. Block (b,G): oh in [2G,2G+2).
// Wave = 16 px x all 64 co. NEW vs R17: e1/e2 A-fragments (48 KB) staged ONCE
// per block into LDS (ends the per-wave 72KB L1-thrash / 451MB L2 A-stream that
// the R18 ablation proved was ~90% of the kernel). Shared expert stays on the
// global 2-deep-pipeline path (24 KB, now L1-resident device-wide).
__global__ __launch_bounds__(448, 2) void k_main(
    const float* __restrict__ x,
    const float* __restrict__ w_gate,
    const float* __restrict__ eB, const float* __restrict__ sB,
    const float* __restrict__ elnw, const float* __restrict__ elnb,
    const float* __restrict__ slnw, const float* __restrict__ slnb,
    float* __restrict__ out, float* __restrict__ loss_out) {
  __shared__ __align__(16) ushort Wnd[3 * WR * PWL];     // 15312 B
  __shared__ __align__(16) ushort Apw[2 * EXP_USH];      // 49152 B (e1,e2 A-frags)

  const int tid  = threadIdx.x;
  const int lane = tid & 63;
  const int w    = tid >> 6;      // 0..6 (tile within group)
  const int b    = blockIdx.x / NGRP;
  const int G    = blockIdx.x % NGRP;

  // ---- stage window: ih = 8G-3 .. 8G+7 per ci, cols padded +4/+4 ----
  for (int i = tid; i < 3 * WR * 28; i += 448) {
    const int j8 = i % 28;
    const int rr = i / 28;              // ci*11 + wr
    const int ci = rr / WR;
    const int wr = rr - ci * WR;
    const int ih = 8 * G + wr - 3;
    uint2 lo = {0u, 0u}, hi = {0u, 0u};
    if ((unsigned)ih < (unsigned)HIN) {
      const float4* xr = reinterpret_cast<const float4*>(
          x + ((size_t)(b * CIN + ci) * HIN + ih) * WIN);
      const float4 f0 = xr[2 * j8];
      const float4 f1 = xr[2 * j8 + 1];
      lo.x = (uint)f2bf(f0.x) | ((uint)f2bf(f0.y) << 16);
      lo.y = (uint)f2bf(f0.z) | ((uint)f2bf(f0.w) << 16);
      hi.x = (uint)f2bf(f1.x) | ((uint)f2bf(f1.y) << 16);
      hi.y = (uint)f2bf(f1.z) | ((uint)f2bf(f1.w) << 16);
    }
    *reinterpret_cast<uint2*>(&Wnd[rr * PWL + 8 * j8 + 4]) = lo;
    *reinterpret_cast<uint2*>(&Wnd[rr * PWL + 8 * j8 + 8]) = hi;
    if (j8 == 0)  { const uint2 z = {0u, 0u}; *reinterpret_cast<uint2*>(&Wnd[rr * PWL]) = z; }
    if (j8 == 27) { const uint2 z = {0u, 0u}; *reinterpret_cast<uint2*>(&Wnd[rr * PWL + 228]) = z; }
  }

  // ---- gating from partials (overlaps staging latency) ----
  float gi[3];
  #pragma unroll
  for (int c = 0; c < 3; ++c) {
    float s = 0.f;
    #pragma unroll
    for (int p = 0; p < 8; ++p) s += g_gatepart[(b * 3 + c) * 8 + p];
    gi[c] = s * (1.f / (float)(HIN * WIN));
  }
  float best1 = -1e30f, best2 = -1e30f;
  int i1 = 0, i2 = 0;
  #pragma unroll
  for (int e = 0; e < NEXP; ++e) {
    const float lg = gi[0] * w_gate[e] + gi[1] * w_gate[8 + e] + gi[2] * w_gate[16 + e];
    if (lg > best1) { best2 = best1; i2 = i1; best1 = lg; i1 = e; }
    else if (lg > best2) { best2 = lg; i2 = e; }
  }
  const float e21 = expf(best2 - best1);
  const float g1 = 1.f / (1.f + e21);
  const float g2 = e21 / (1.f + e21);
  const int e1 = __builtin_amdgcn_readfirstlane(i1);
  const int e2 = __builtin_amdgcn_readfirstlane(i2);

  // ---- stage e1/e2 A-fragments into LDS (48 KB, coalesced, once/block) ----
  {
    const int eidx01[2] = {e1, e2};
    for (int i = tid; i < 2 * (EXP_USH / 8); i += 448) {   // 3072 uint4
      const int s = (i >= (EXP_USH / 8)) ? 1 : 0;
      const int c = i - s * (EXP_USH / 8);
      const uint4 v = *reinterpret_cast<const uint4*>(
          g_pw3 + (size_t)eidx01[s] * EXP_USH + c * 8);
      *reinterpret_cast<uint4*>(&Apw[s * EXP_USH + c * 8]) = v;
    }
  }

  // ---- aux loss: block 0, wave 0 (lane = image) ----
  if (blockIdx.x == 0 && w == 0) {
    float mg1 = 0.f, mg2 = 0.f;
    int me1 = -1, me2 = -1;
    if (lane < BATCH) {
      float a[3];
      #pragma unroll
      for (int c = 0; c < 3; ++c) {
        float s = 0.f;
        #pragma unroll
        for (int p = 0; p < 8; ++p) s += g_gatepart[(lane * 3 + c) * 8 + p];
        a[c] = s * (1.f / (float)(HIN * WIN));
      }
      float b1 = -1e30f, b2 = -1e30f;
      int j1 = 0, j2 = 0;
      #pragma unroll
      for (int e = 0; e < NEXP; ++e) {
        const float lg = a[0] * w_gate[e] + a[1] * w_gate[8 + e] + a[2] * w_gate[16 + e];
        if (lg > b1) { b2 = b1; j2 = j1; b1 = lg; j1 = e; }
        else if (lg > b2) { b2 = lg; j2 = e; }
      }
      const float q = expf(b2 - b1);
      mg1 = 1.f / (1.f + q); mg2 = q / (1.f + q);
      me1 = j1; me2 = j2;
    }
    float imp[NEXP], lod[NEXP];
    #pragma unroll
    for (int e = 0; e < NEXP; ++e) {
      float ie = ((me1 == e) ? mg1 : 0.f) + ((me2 == e) ? mg2 : 0.f);
      float le = (((me1 == e) && (mg1 > 0.f)) ? 1.f : 0.f)
               + (((me2 == e) && (mg2 > 0.f)) ? 1.f : 0.f);
      #pragma unroll
      for (int o = 32; o > 0; o >>= 1) { ie += __shfl_xor(ie, o, 64); le += __shfl_xor(le, o, 64); }
      imp[e] = ie; lod[e] = le;
    }
    if (lane == 0) {
      float mi = 0.f, ml = 0.f;
      #pragma unroll
      for (int e = 0; e < NEXP; ++e) { mi += imp[e]; ml += lod[e]; }
      mi *= (1.f / NEXP); ml *= (1.f / NEXP);
      float vi = 0.f, vl = 0.f;
      #pragma unroll
      for (int e = 0; e < NEXP; ++e) {
        const float di = imp[e] - mi; vi += di * di;
        const float dl = lod[e] - ml; vl += dl * dl;
      }
      vi *= (1.f / (NEXP - 1)); vl *= (1.f / (NEXP - 1));
      loss_out[0] = 0.01f * (vi / (mi * mi + 1e-10f) + vl / (ml * ml + 1e-10f));
    }
  }

  const int m    = lane >> 4;       // k-chunk / co-subrow group
  const int colA = lane & 15;       // pixel within tile
  const float ge[3] = {g1, g2, 1.f};

  // per-lane window row offsets per ks (k' row r = 4ks+m; r>20 clamps, wt=0)
  int Crow[NKS];
  #pragma unroll
  for (int ks = 0; ks < NKS; ++ks) {
    int r = 4 * ks + m;
    r = r > 20 ? 20 : r;
    const int ci = r >= 14 ? 2 : (r >= 7 ? 1 : 0);
    const int kh = r - ci * 7;
    Crow[ks] = (ci * WR + kh) * PWL;
  }

  // my single pixel-tile
  const int pg = G * 112 + w * 16 + colA;   // global pixel in image
  const int oh = pg / WOUT;
  const int ow = pg - oh * WOUT;
  const int baseB = ((oh - 2 * G) * 4) * PWL + ow * 4;

  __syncthreads();   // window + A-frags visible; waves independent from here on

  __builtin_amdgcn_s_setprio(1);

  float outAcc[16];
  #pragma unroll
  for (int j = 0; j < 16; ++j) outAcc[j] = 0.f;

  // shared epilogue: bias + wave-local LN + gated accumulate into outAcc
  auto epilogue = [&](int e, int es, f32x4 (&acc)[4]) {
    const float* bsrc = (e < 2) ? eB + es * COUT : sB;
    const float* wsrc = (e < 2) ? elnw + es * COUT : slnw;
    const float* csrc = (e < 2) ? elnb + es * COUT : slnb;
    float s = 0.f, q = 0.f;
    #pragma unroll
    for (int f = 0; f < 4; ++f) {
      const float4 b4 = *reinterpret_cast<const float4*>(bsrc + f * 16 + m * 4);
      #pragma unroll
      for (int r = 0; r < 4; ++r) {
        const float y = acc[f][r] + (&b4.x)[r];
        acc[f][r] = y;
        s += y; q += y * y;
      }
    }
    s += __shfl_xor(s, 16, 64); s += __shfl_xor(s, 32, 64);
    q += __shfl_xor(q, 16, 64); q += __shfl_xor(q, 32, 64);
    const float u  = s * (1.f / 64.f);
    const float vv = q * (1.f / 64.f) - u * u;
    const float rs = rsqrtf(vv + LN_EPS_F);
    #pragma unroll
    for (int f = 0; f < 4; ++f) {
      const float4 lw4 = *reinterpret_cast<const float4*>(wsrc + f * 16 + m * 4);
      const float4 lb4 = *reinterpret_cast<const float4*>(csrc + f * 16 + m * 4);
      #pragma unroll
      for (int r = 0; r < 4; ++r)
        outAcc[f * 4 + r] += ge[e] * ((&lw4.x)[r] * (acc[f][r] - u) * rs + (&lb4.x)[r]);
    }
  };

  // ---- experts e1, e2: A-fragments from LDS ----
  {
    const int eidx01[2] = {e1, e2};
    #pragma unroll
    for (int e = 0; e < 2; ++e) {
      f32x4 acc[4];
      #pragma unroll
      for (int f = 0; f < 4; ++f) acc[f] = (f32x4){0.f, 0.f, 0.f, 0.f};
      const ushort* ap = &Apw[e * EXP_USH + lane * 8];
      #pragma unroll
      for (int ks = 0; ks < NKS; ++ks) {
        bf16x8 a4[4];
        #pragma unroll
        for (int f = 0; f < 4; ++f)
          a4[f] = __builtin_bit_cast(bf16x8,
              *reinterpret_cast<const uint4*>(ap + (f * 6 + ks) * 512));
        const ushort* p = &Wnd[baseB + Crow[ks]];
        const uint2 lo = *reinterpret_cast<const uint2*>(p);
        const uint2 hi = *reinterpret_cast<const uint2*>(p + 4);
        const uint4 raw = {lo.x, lo.y, hi.x, hi.y};
        const bf16x8 bf = __builtin_bit_cast(bf16x8, raw);
        #pragma unroll
        for (int f = 0; f < 4; ++f)
          acc[f] = __builtin_amdgcn_mfma_f32_16x16x32_bf16(a4[f], bf, acc[f], 0, 0, 0);
      }
      epilogue(e, eidx01[e], acc);
    }
  }

  // ---- shared expert: A from global (L1-resident, 2-deep pipeline) ----
  {
    f32x4 acc[4];
    #pragma unroll
    for (int f = 0; f < 4; ++f) acc[f] = (f32x4){0.f, 0.f, 0.f, 0.f};
    const ushort* ape = g_pw3 + (size_t)8 * EXP_USH + lane * 8;
    bf16x8 aCur0 = __builtin_bit_cast(bf16x8, *reinterpret_cast<const uint4*>(ape + (0 * 6 + 0) * 512));
    bf16x8 aCur1 = __builtin_bit_cast(bf16x8, *reinterpret_cast<const uint4*>(ape + (1 * 6 + 0) * 512));
    bf16x8 aCur2 = __builtin_bit_cast(bf16x8, *reinterpret_cast<const uint4*>(ape + (2 * 6 + 0) * 512));
    bf16x8 aCur3 = __builtin_bit_cast(bf16x8, *reinterpret_cast<const uint4*>(ape + (3 * 6 + 0) * 512));
    #pragma unroll
    for (int ks = 0; ks < NKS; ++ks) {
      bf16x8 aNxt0, aNxt1, aNxt2, aNxt3;
      if (ks < NKS - 1) {
        aNxt0 = __builtin_bit_cast(bf16x8, *reinterpret_cast<const uint4*>(ape + (0 * 6 + ks + 1) * 512));
        aNxt1 = __builtin_bit_cast(bf16x8, *reinterpret_cast<const uint4*>(ape + (1 * 6 + ks + 1) * 512));
        aNxt2 = __builtin_bit_cast(bf16x8, *reinterpret_cast<const uint4*>(ape + (2 * 6 + ks + 1) * 512));
        aNxt3 = __builtin_bit_cast(bf16x8, *reinterpret_cast<const uint4*>(ape + (3 * 6 + ks + 1) * 512));
      }
      const ushort* p = &Wnd[baseB + Crow[ks]];
      const uint2 lo = *reinterpret_cast<const uint2*>(p);
      const uint2 hi = *reinterpret_cast<const uint2*>(p + 4);
      const uint4 raw = {lo.x, lo.y, hi.x, hi.y};
      const bf16x8 bf = __builtin_bit_cast(bf16x8, raw);
      acc[0] = __builtin_amdgcn_mfma_f32_16x16x32_bf16(aCur0, bf, acc[0], 0, 0, 0);
      acc[1] = __builtin_amdgcn_mfma_f32_16x16x32_bf16(aCur1, bf, acc[1], 0, 0, 0);
      acc[2] = __builtin_amdgcn_mfma_f32_16x16x32_bf16(aCur2, bf, acc[2], 0, 0, 0);
      acc[3] = __builtin_amdgcn_mfma_f32_16x16x32_bf16(aCur3, bf, acc[3], 0, 0, 0);
      if (ks < NKS - 1) { aCur0 = aNxt0; aCur1 = aNxt1; aCur2 = aNxt2; aCur3 = aNxt3; }
    }
    epilogue(2, 8, acc);
  }

  __builtin_amdgcn_s_setprio(0);

  // ---- NONTEMPORAL stores: co = f*16 + m*4 + r, pixel pg ----
  float* const outb = out + (size_t)b * (COUT * NPIX);
  #pragma unroll
  for (int f = 0; f < 4; ++f)
    #pragma unroll
    for (int r = 0; r < 4; ++r)
      __builtin_nontemporal_store(outAcc[f * 4 + r],
          outb + (size_t)(f * 16 + m * 4 + r) * NPIX + pg);
}

// ---------------- launch ----------------
extern "C" void kernel_launch(void* const* d_in, const int* in_sizes, int n_in,
                              void* d_out, int out_size, void* d_ws, size_t ws_size,
                              hipStream_t stream) {
  const float* x    = (const float*)d_in[0];
  const float* eW   = (const float*)d_in[1];
  const float* eB   = (const float*)d_in[2];
  const float* elnw = (const float*)d_in[3];
  const float* elnb = (const float*)d_in[4];
  const float* sW   = (const float*)d_in[5];
  const float* sB   = (const float*)d_in[6];
  const float* slnw = (const float*)d_in[7];
  const float* slnb = (const float*)d_in[8];
  const float* wg   = (const float*)d_in[9];
  float* out = (float*)d_out;

  float* loss_ptr = out + (size_t)BATCH * COUT * NPIX;  // element 6422528

  k_pre<<<N_GPART + N_REPACK, 256, 0, stream>>>(x, eW, sW);
  k_main<<<BATCH * NGRP, 448, 0, stream>>>(x, wg, eB, sB, elnw, elnb,
                                           slnw, slnb, out, loss_ptr);
}

// Round 20
// 41.806 us; speedup vs baseline: 18.6095x; 1.0116x over previous
//
#include <hip/hip_runtime.h>
#include <cstdint>
#include <cstddef>

// ---- problem constants ----
static constexpr int BATCH = 32;
static constexpr int CIN   = 3;
static constexpr int HIN   = 224, WIN = 224;
static constexpr int COUT  = 64;
static constexpr int HOUT  = 56, WOUT = 56;
static constexpr int NPIX  = HOUT * WOUT;     // 3136
static constexpr int NEXP  = 8;
static constexpr int KROWS = 21;              // ci*7 + kh
static constexpr int NKS   = 6;               // K-steps of 32
static constexpr int NGRP  = 28;              // 2-oh-row groups per image (112 px)
static constexpr int PWL   = 232;             // window row length (ushorts): 4+224+4
static constexpr int WR    = 11;              // window rows per ci (2*4 + 3)
static constexpr float LN_EPS_F = 1e-6f;

// fragment-coalesced weight buffer: [e(9)][f(4)][ks(6)][lane(64)][8]
static constexpr int PW3_ELEMS = 9 * 4 * 6 * 64 * 8;   // 110592
static constexpr int EXP_USH   = 4 * 6 * 512;          // 12288 ushorts per expert

// k_pre partition: gate partial sums (768) + weight repack (432)
static constexpr int N_GPART  = BATCH * CIN * 8;                  // 768
static constexpr int N_REPACK = (PW3_ELEMS + 255) / 256;          // 432

typedef __bf16 bf16x8 __attribute__((ext_vector_type(8)));
typedef float  f32x4  __attribute__((ext_vector_type(4)));

// ---- device-global scratch ----
__device__ __align__(16) ushort g_pw3[PW3_ELEMS];   // bf16 weights, fragment order
__device__ float g_gatepart[BATCH * CIN * 8];       // partial plane sums

__device__ __forceinline__ ushort f2bf(float f) {
  uint u = __float_as_uint(f);
  uint r = (u + 0x7FFFu + ((u >> 16) & 1u)) >> 16;  // RNE
  return (ushort)r;
}

// ---------------- kernel 1: gate partial sums (0..767) / repack (768..1199) ---
__global__ __launch_bounds__(256) void k_pre(const float* __restrict__ x,
                                             const float* __restrict__ eW,
                                             const float* __restrict__ sW) {
  const int bid = blockIdx.x;
  if (bid < N_GPART) {
    const int plane = bid >> 3;
    const int slice = bid & 7;
    const float4* p4 = reinterpret_cast<const float4*>(x + (size_t)plane * (HIN * WIN));
    float s = 0.f;
    const int i0 = slice * 1568;                // 12544/8 float4 per slice
    for (int i = i0 + (int)threadIdx.x; i < i0 + 1568; i += 256) {
      const float4 v = p4[i];
      s += v.x + v.y + v.z + v.w;
    }
    __shared__ float red[256];
    red[threadIdx.x] = s;
    __syncthreads();
    for (int off = 128; off > 0; off >>= 1) {
      if ((int)threadIdx.x < off) red[threadIdx.x] += red[threadIdx.x + off];
      __syncthreads();
    }
    if (threadIdx.x == 0) g_gatepart[bid] = red[0];
  } else {
    // repack -> fragment order: idx = ((e*4+f)*6+ks)*512 + lane*8 + j
    const int idx = (bid - N_GPART) * 256 + threadIdx.x;
    if (idx >= PW3_ELEMS) return;
    const int j    = idx & 7;
    const int lane = (idx >> 3) & 63;
    const int ks   = (idx >> 9) % 6;
    const int fe   = idx / (512 * 6);   // e*4 + f
    const int f    = fe & 3;
    const int e    = fe >> 2;
    const int m    = lane >> 4;
    const int colA = lane & 15;
    const int co   = f * 16 + colA;
    const int r    = ks * 4 + m;
    float v = 0.f;
    if (j >= 1 && r < KROWS) {
      const int k = r * 7 + (j - 1);
      v = (e < 8) ? eW[(size_t)(e * COUT + co) * 147 + k]
                  : sW[(size_t)co * 147 + k];
    }
    g_pw3[idx] = f2bf(v);
  }
}

// ---------------- kernel 2: MFMA conv + LN + combine, batched-wait edition ----
// 896 blocks x 448 threads (7 waves). Block (b,G): oh in [2G,2G+2) = 112 px.
// Wave = 16 px x all 64 co. vs R19: B-fragments hoisted to registers (one
// wait), A-loads batched 6-at-a-time per co-row (one wait per 6 loads, then 6
// MFMAs) — exposed wait-events per wave drop ~36 -> ~14 (R18 ablation showed
// the A+MFMA phase's exposed waits ARE the kernel).
__global__ __launch_bounds__(448, 2) void k_main(
    const float* __restrict__ x,
    const float* __restrict__ w_gate,
    const float* __restrict__ eB, const float* __restrict__ sB,
    const float* __restrict__ elnw, const float* __restrict__ elnb,
    const float* __restrict__ slnw, const float* __restrict__ slnb,
    float* __restrict__ out, float* __restrict__ loss_out) {
  __shared__ __align__(16) ushort Wnd[3 * WR * PWL];     // 15312 B
  __shared__ __align__(16) ushort Apw[2 * EXP_USH];      // 49152 B (e1,e2 A-frags)

  const int tid  = threadIdx.x;
  const int lane = tid & 63;
  const int w    = tid >> 6;      // 0..6 (tile within group)
  const int b    = blockIdx.x / NGRP;
  const int G    = blockIdx.x % NGRP;

  // ---- stage window: ih = 8G-3 .. 8G+7 per ci, cols padded +4/+4 ----
  for (int i = tid; i < 3 * WR * 28; i += 448) {
    const int j8 = i % 28;
    const int rr = i / 28;              // ci*11 + wr
    const int ci = rr / WR;
    const int wr = rr - ci * WR;
    const int ih = 8 * G + wr - 3;
    uint2 lo = {0u, 0u}, hi = {0u, 0u};
    if ((unsigned)ih < (unsigned)HIN) {
      const float4* xr = reinterpret_cast<const float4*>(
          x + ((size_t)(b * CIN + ci) * HIN + ih) * WIN);
      const float4 f0 = xr[2 * j8];
      const float4 f1 = xr[2 * j8 + 1];
      lo.x = (uint)f2bf(f0.x) | ((uint)f2bf(f0.y) << 16);
      lo.y = (uint)f2bf(f0.z) | ((uint)f2bf(f0.w) << 16);
      hi.x = (uint)f2bf(f1.x) | ((uint)f2bf(f1.y) << 16);
      hi.y = (uint)f2bf(f1.z) | ((uint)f2bf(f1.w) << 16);
    }
    *reinterpret_cast<uint2*>(&Wnd[rr * PWL + 8 * j8 + 4]) = lo;
    *reinterpret_cast<uint2*>(&Wnd[rr * PWL + 8 * j8 + 8]) = hi;
    if (j8 == 0)  { const uint2 z = {0u, 0u}; *reinterpret_cast<uint2*>(&Wnd[rr * PWL]) = z; }
    if (j8 == 27) { const uint2 z = {0u, 0u}; *reinterpret_cast<uint2*>(&Wnd[rr * PWL + 228]) = z; }
  }

  // ---- gating from partials (overlaps staging latency) ----
  float gi[3];
  #pragma unroll
  for (int c = 0; c < 3; ++c) {
    float s = 0.f;
    #pragma unroll
    for (int p = 0; p < 8; ++p) s += g_gatepart[(b * 3 + c) * 8 + p];
    gi[c] = s * (1.f / (float)(HIN * WIN));
  }
  float best1 = -1e30f, best2 = -1e30f;
  int i1 = 0, i2 = 0;
  #pragma unroll
  for (int e = 0; e < NEXP; ++e) {
    const float lg = gi[0] * w_gate[e] + gi[1] * w_gate[8 + e] + gi[2] * w_gate[16 + e];
    if (lg > best1) { best2 = best1; i2 = i1; best1 = lg; i1 = e; }
    else if (lg > best2) { best2 = lg; i2 = e; }
  }
  const float e21 = expf(best2 - best1);
  const float g1 = 1.f / (1.f + e21);
  const float g2 = e21 / (1.f + e21);
  const int e1 = __builtin_amdgcn_readfirstlane(i1);
  const int e2 = __builtin_amdgcn_readfirstlane(i2);

  // ---- stage e1/e2 A-fragments into LDS (48 KB, coalesced, once/block) ----
  {
    const int eidx01[2] = {e1, e2};
    for (int i = tid; i < 2 * (EXP_USH / 8); i += 448) {   // 3072 uint4
      const int s = (i >= (EXP_USH / 8)) ? 1 : 0;
      const int c = i - s * (EXP_USH / 8);
      const uint4 v = *reinterpret_cast<const uint4*>(
          g_pw3 + (size_t)eidx01[s] * EXP_USH + c * 8);
      *reinterpret_cast<uint4*>(&Apw[s * EXP_USH + c * 8]) = v;
    }
  }

  // ---- aux loss: block 0, wave 0 (lane = image) ----
  if (blockIdx.x == 0 && w == 0) {
    float mg1 = 0.f, mg2 = 0.f;
    int me1 = -1, me2 = -1;
    if (lane < BATCH) {
      float a[3];
      #pragma unroll
      for (int c = 0; c < 3; ++c) {
        float s = 0.f;
        #pragma unroll
        for (int p = 0; p < 8; ++p) s += g_gatepart[(lane * 3 + c) * 8 + p];
        a[c] = s * (1.f / (float)(HIN * WIN));
      }
      float b1 = -1e30f, b2 = -1e30f;
      int j1 = 0, j2 = 0;
      #pragma unroll
      for (int e = 0; e < NEXP; ++e) {
        const float lg = a[0] * w_gate[e] + a[1] * w_gate[8 + e] + a[2] * w_gate[16 + e];
        if (lg > b1) { b2 = b1; j2 = j1; b1 = lg; j1 = e; }
        else if (lg > b2) { b2 = lg; j2 = e; }
      }
      const float q = expf(b2 - b1);
      mg1 = 1.f / (1.f + q); mg2 = q / (1.f + q);
      me1 = j1; me2 = j2;
    }
    float imp[NEXP], lod[NEXP];
    #pragma unroll
    for (int e = 0; e < NEXP; ++e) {
      float ie = ((me1 == e) ? mg1 : 0.f) + ((me2 == e) ? mg2 : 0.f);
      float le = (((me1 == e) && (mg1 > 0.f)) ? 1.f : 0.f)
               + (((me2 == e) && (mg2 > 0.f)) ? 1.f : 0.f);
      #pragma unroll
      for (int o = 32; o > 0; o >>= 1) { ie += __shfl_xor(ie, o, 64); le += __shfl_xor(le, o, 64); }
      imp[e] = ie; lod[e] = le;
    }
    if (lane == 0) {
      float mi = 0.f, ml = 0.f;
      #pragma unroll
      for (int e = 0; e < NEXP; ++e) { mi += imp[e]; ml += lod[e]; }
      mi *= (1.f / NEXP); ml *= (1.f / NEXP);
      float vi = 0.f, vl = 0.f;
      #pragma unroll
      for (int e = 0; e < NEXP; ++e) {
        const float di = imp[e] - mi; vi += di * di;
        const float dl = lod[e] - ml; vl += dl * dl;
      }
      vi *= (1.f / (NEXP - 1)); vl *= (1.f / (NEXP - 1));
      loss_out[0] = 0.01f * (vi / (mi * mi + 1e-10f) + vl / (ml * ml + 1e-10f));
    }
  }

  const int m    = lane >> 4;       // k-chunk / co-subrow group
  const int colA = lane & 15;       // pixel within tile
  const float ge[3] = {g1, g2, 1.f};

  // per-lane window row offsets per ks (k' row r = 4ks+m; r>20 clamps, wt=0)
  int Crow[NKS];
  #pragma unroll
  for (int ks = 0; ks < NKS; ++ks) {
    int r = 4 * ks + m;
    r = r > 20 ? 20 : r;
    const int ci = r >= 14 ? 2 : (r >= 7 ? 1 : 0);
    const int kh = r - ci * 7;
    Crow[ks] = (ci * WR + kh) * PWL;
  }

  // my single pixel-tile
  const int pg = G * 112 + w * 16 + colA;   // global pixel in image
  const int oh = pg / WOUT;
  const int ow = pg - oh * WOUT;
  const int baseB = ((oh - 2 * G) * 4) * PWL + ow * 4;

  __syncthreads();   // window + A-frags visible; waves independent from here on

  __builtin_amdgcn_s_setprio(1);

  // ---- hoist ALL B-fragments into registers (6 LDS reads, ONE wait) ----
  bf16x8 bfr[NKS];
  #pragma unroll
  for (int ks = 0; ks < NKS; ++ks) {
    const ushort* p = &Wnd[baseB + Crow[ks]];
    const uint2 lo = *reinterpret_cast<const uint2*>(p);
    const uint2 hi = *reinterpret_cast<const uint2*>(p + 4);
    const uint4 raw = {lo.x, lo.y, hi.x, hi.y};
    bfr[ks] = __builtin_bit_cast(bf16x8, raw);
  }

  float outAcc[16];
  #pragma unroll
  for (int j = 0; j < 16; ++j) outAcc[j] = 0.f;

  // shared epilogue: bias + wave-local LN + gated accumulate into outAcc
  auto epilogue = [&](int e, int es, f32x4 (&acc)[4]) {
    const float* bsrc = (e < 2) ? eB + es * COUT : sB;
    const float* wsrc = (e < 2) ? elnw + es * COUT : slnw;
    const float* csrc = (e < 2) ? elnb + es * COUT : slnb;
    float s = 0.f, q = 0.f;
    #pragma unroll
    for (int f = 0; f < 4; ++f) {
      const float4 b4 = *reinterpret_cast<const float4*>(bsrc + f * 16 + m * 4);
      #pragma unroll
      for (int r = 0; r < 4; ++r) {
        const float y = acc[f][r] + (&b4.x)[r];
        acc[f][r] = y;
        s += y; q += y * y;
      }
    }
    s += __shfl_xor(s, 16, 64); s += __shfl_xor(s, 32, 64);
    q += __shfl_xor(q, 16, 64); q += __shfl_xor(q, 32, 64);
    const float u  = s * (1.f / 64.f);
    const float vv = q * (1.f / 64.f) - u * u;
    const float rs = rsqrtf(vv + LN_EPS_F);
    #pragma unroll
    for (int f = 0; f < 4; ++f) {
      const float4 lw4 = *reinterpret_cast<const float4*>(wsrc + f * 16 + m * 4);
      const float4 lb4 = *reinterpret_cast<const float4*>(csrc + f * 16 + m * 4);
      #pragma unroll
      for (int r = 0; r < 4; ++r)
        outAcc[f * 4 + r] += ge[e] * ((&lw4.x)[r] * (acc[f][r] - u) * rs + (&lb4.x)[r]);
    }
  };

  // ---- experts e1, e2: A from LDS, batched 6-at-a-time per co-row ----
  {
    const int eidx01[2] = {e1, e2};
    #pragma unroll
    for (int e = 0; e < 2; ++e) {
      f32x4 acc[4];
      #pragma unroll
      for (int f = 0; f < 4; ++f) acc[f] = (f32x4){0.f, 0.f, 0.f, 0.f};
      const ushort* ap = &Apw[e * EXP_USH + lane * 8];
      #pragma unroll
      for (int f = 0; f < 4; ++f) {
        bf16x8 aF[NKS];
        #pragma unroll
        for (int ks = 0; ks < NKS; ++ks)
          aF[ks] = __builtin_bit_cast(bf16x8,
              *reinterpret_cast<const uint4*>(ap + (f * 6 + ks) * 512));
        #pragma unroll
        for (int ks = 0; ks < NKS; ++ks)
          acc[f] = __builtin_amdgcn_mfma_f32_16x16x32_bf16(aF[ks], bfr[ks], acc[f], 0, 0, 0);
      }
      epilogue(e, eidx01[e], acc);
    }
  }

  // ---- shared expert: A from global, batched 6-at-a-time per co-row ----
  {
    f32x4 acc[4];
    #pragma unroll
    for (int f = 0; f < 4; ++f) acc[f] = (f32x4){0.f, 0.f, 0.f, 0.f};
    const ushort* ape = g_pw3 + (size_t)8 * EXP_USH + lane * 8;
    #pragma unroll
    for (int f = 0; f < 4; ++f) {
      bf16x8 aF[NKS];
      #pragma unroll
      for (int ks = 0; ks < NKS; ++ks)
        aF[ks] = __builtin_bit_cast(bf16x8,
            *reinterpret_cast<const uint4*>(ape + (f * 6 + ks) * 512));
      #pragma unroll
      for (int ks = 0; ks < NKS; ++ks)
        acc[f] = __builtin_amdgcn_mfma_f32_16x16x32_bf16(aF[ks], bfr[ks], acc[f], 0, 0, 0);
    }
    epilogue(2, 8, acc);
  }

  __builtin_amdgcn_s_setprio(0);

  // ---- NONTEMPORAL stores: co = f*16 + m*4 + r, pixel pg ----
  float* const outb = out + (size_t)b * (COUT * NPIX);
  #pragma unroll
  for (int f = 0; f < 4; ++f)
    #pragma unroll
    for (int r = 0; r < 4; ++r)
      __builtin_nontemporal_store(outAcc[f * 4 + r],
          outb + (size_t)(f * 16 + m * 4 + r) * NPIX + pg);
}

// ---------------- launch ----------------
extern "C" void kernel_launch(void* const* d_in, const int* in_sizes, int n_in,
                              void* d_out, int out_size, void* d_ws, size_t ws_size,
                              hipStream_t stream) {
  const float* x    = (const float*)d_in[0];
  const float* eW   = (const float*)d_in[1];
  const float* eB   = (const float*)d_in[2];
  const float* elnw = (const float*)d_in[3];
  const float* elnb = (const float*)d_in[4];
  const float* sW   = (const float*)d_in[5];
  const float* sB   = (const float*)d_in[6];
  const float* slnw = (const float*)d_in[7];
  const float* slnb = (const float*)d_in[8];
  const float* wg   = (const float*)d_in[9];
  float* out = (float*)d_out;

  float* loss_ptr = out + (size_t)BATCH * COUT * NPIX;  // element 6422528

  k_pre<<<N_GPART + N_REPACK, 256, 0, stream>>>(x, eW, sW);
  k_main<<<BATCH * NGRP, 448, 0, stream>>>(x, wg, eB, sB, elnw, elnb,
                                           slnw, slnb, out, loss_ptr);
}